// Round 6
// baseline (152.847 us; speedup 1.0000x reference)
//
#include <hip/hip_runtime.h>
#include <hip/hip_bf16.h>
#include <math.h>

#define DD 128
#define SS 1024
#define NROWS 8192
#define EPSF 1e-7f
#define LN_EPSF 1e-3f
#define TCUT 30.0f

typedef __attribute__((ext_vector_type(8))) short bf16x8;
typedef __attribute__((ext_vector_type(4))) float f32x4;
typedef __attribute__((ext_vector_type(16))) float f32x16;

__device__ __forceinline__ void gload_lds16(const void* g, void* l) {
    __builtin_amdgcn_global_load_lds(
        (const __attribute__((address_space(1))) unsigned int*)g,
        (__attribute__((address_space(3))) unsigned int*)l, 16, 0, 0);
}
__device__ __forceinline__ short f2bf(float v) {
    union { __hip_bfloat16 h; short s; } u;
    u.h = __float2bfloat16(v);
    return u.s;
}
__device__ __forceinline__ float bf2f(short s) {
    union { __hip_bfloat16 h; short s; } u; u.s = s;
    return __bfloat162float(u.h);
}

// ---- K0a: emb -> bf16 fragment-linear: embh3[(d*4+js)*4096 + (ks*64+l)*8+e]
//      = emb[d][js*32 + (l&31)][ks*16 + (l>>5)*8 + e]
__global__ __launch_bounds__(256) void k0a_emb(const float* __restrict__ emb,
                                               short* __restrict__ embh3) {
    __shared__ float lt[32][128];
    int d = blockIdx.x, js = blockIdx.y, t = threadIdx.x;
    {
        int jl = t >> 3, k0 = (t & 7) * 16;
        const float4* src = (const float4*)(emb + (size_t)d * 16384
                                            + (size_t)(js * 32 + jl) * 128 + k0);
#pragma unroll
        for (int q = 0; q < 4; ++q) *(float4*)&lt[jl][k0 + q * 4] = src[q];
    }
    __syncthreads();
    int ks = t >> 5, l0 = (t & 31) * 2;
    union { bf16x8 v[2]; short s[16]; } ob;
#pragma unroll
    for (int li = 0; li < 2; ++li) {
        int l = l0 + li;
        const float* p = &lt[l & 31][ks * 16 + (l >> 5) * 8];
#pragma unroll
        for (int e = 0; e < 8; ++e) ob.s[li * 8 + e] = f2bf(p[e]);
    }
    short* dst = embh3 + (size_t)(d * 4 + js) * 4096 + (size_t)t * 16;
    *(bf16x8*)dst = ob.v[0];
    *(bf16x8*)(dst + 8) = ob.v[1];
}

// ---- K0w: split Wq|Wm into bf16 hi/lo fragment-linear for k1 --------------
__global__ __launch_bounds__(256) void k0w_split(const float* __restrict__ Wq,
        const float* __restrict__ Wm, short* __restrict__ Wfrag) {
    int T = blockIdx.x * 256 + threadIdx.x;       // 65536 total
    int e = T & 7, l = (T >> 3) & 63, ks = (T >> 9) & 3, nt = (T >> 11) & 7,
        mat = (T >> 14) & 1;
    int k = ks * 32 + ((l >> 4) & 3) * 8 + e;
    int c = nt * 16 + (l & 15);
    float v = (mat ? Wm : Wq)[k * 128 + c];
    short h = f2bf(v);
    float lo = v - bf2f(h);
    Wfrag[((((size_t)(mat * 2 + 0) * 8 + nt) * 4 + ks) * 64 + l) * 8 + e] = h;
    Wfrag[((((size_t)(mat * 2 + 1) * 8 + nt) * 4 + ks) * 64 + l) * 8 + e] = f2bf(lo);
}

// ---- K0c: x -> xh2/xl2 (frag-linear for k1) + w,c scalars ------------------
__global__ __launch_bounds__(256) void k0c_xsplit(const float* __restrict__ x,
        const float* __restrict__ Ww, const float* __restrict__ bw,
        const float* __restrict__ Wc, const float* __restrict__ bc,
        short* __restrict__ xh2, short* __restrict__ xl2,
        float* __restrict__ scal) {
    __shared__ float xs[32][129];
    int rb = blockIdx.x, t = threadIdx.x;
    {
        int r = t >> 3, d0 = (t & 7) * 16;
        const float4* src = (const float4*)(x + (size_t)(rb * 32 + r) * 128 + d0);
#pragma unroll
        for (int q = 0; q < 4; ++q) *(float4*)&xs[r][d0 + q * 4] = src[q];
    }
    __syncthreads();
    int ks = (t >> 5) & 3, rf = t >> 7, l0 = (t & 31) * 2;
    union { bf16x8 v[2]; short s[16]; } hb, lb;
#pragma unroll
    for (int li = 0; li < 2; ++li) {
        int l = l0 + li;
        const float* p = &xs[rf * 16 + (l & 15)][ks * 32 + ((l >> 4) & 3) * 8];
#pragma unroll
        for (int e = 0; e < 8; ++e) {
            float v = p[e];
            short h = f2bf(v);
            hb.s[li * 8 + e] = h;
            lb.s[li * 8 + e] = f2bf(v - bf2f(h));
        }
    }
    {
        short* d1 = xh2 + (size_t)rb * 4096 + (size_t)t * 16;
        short* d2 = xl2 + (size_t)rb * 4096 + (size_t)t * 16;
        *(bf16x8*)d1 = hb.v[0]; *(bf16x8*)(d1 + 8) = hb.v[1];
        *(bf16x8*)d2 = lb.v[0]; *(bf16x8*)(d2 + 8) = lb.v[1];
    }
    // w, c scalars
    int rr = t >> 3, seg = t & 7;
    float pw = 0.f, pc = 0.f;
#pragma unroll
    for (int dq = 0; dq < 16; ++dq) {
        float xv = xs[rr][seg * 16 + dq];
        pw = fmaf(xv, Ww[seg * 16 + dq], pw);
        pc = fmaf(xv, Wc[seg * 16 + dq], pc);
    }
    pw += __shfl_xor(pw, 1); pw += __shfl_xor(pw, 2); pw += __shfl_xor(pw, 4);
    pc += __shfl_xor(pc, 1); pc += __shfl_xor(pc, 2); pc += __shfl_xor(pc, 4);
    if (seg == 0) {
        scal[(size_t)(rb * 32 + rr) * 4 + 0] = fmaxf(pw + bw[0], 0.f);
        scal[(size_t)(rb * 32 + rr) * 4 + 1] = fmaxf(pc + bc[0], 0.f);
    }
}

// ---- K1: q'/m via split-bf16 MFMA (3 products each), fused epilogue --------
__global__ __launch_bounds__(256) void k1_mfma(
    const short* __restrict__ xh2, const short* __restrict__ xl2,
    const short* __restrict__ Wfrag,
    const float* __restrict__ bq, const float* __restrict__ bm,
    float* __restrict__ mq, float* __restrict__ mo, float* __restrict__ scal)
{
    __shared__ __align__(16) short wl[65536];   // 128 KB
    __shared__ float red[32][4][2];
    int t = threadIdx.x, w = t >> 6, l = t & 63;
    int l15 = l & 15, g = l >> 4;
    int row0 = blockIdx.x * 32;
#pragma unroll
    for (int it = 0; it < 32; ++it)
        gload_lds16(Wfrag + (size_t)(it * 256 + t) * 8, wl + (size_t)(it * 256 + w * 64) * 8);
    const short* xb  = xh2 + (size_t)blockIdx.x * 4096;
    const short* xlb = xl2 + (size_t)blockIdx.x * 4096;
    bf16x8 Ah[2][4], Al[2][4];
#pragma unroll
    for (int rf = 0; rf < 2; ++rf)
#pragma unroll
        for (int ks = 0; ks < 4; ++ks) {
            size_t o = ((size_t)(rf * 4 + ks) * 64 + l) * 8;
            Ah[rf][ks] = *(const bf16x8*)(xb + o);
            Al[rf][ks] = *(const bf16x8*)(xlb + o);
        }
    __syncthreads();
    f32x4 accq[2][2] = {}, accm[2][2] = {};
#pragma unroll
    for (int ntp = 0; ntp < 2; ++ntp) {
        int nt = w * 2 + ntp;
#pragma unroll
        for (int ks = 0; ks < 4; ++ks) {
            bf16x8 bhq = *(const bf16x8*)(wl + ((size_t)(0  + nt) * 4 + ks) * 512 + l * 8);
            bf16x8 blq = *(const bf16x8*)(wl + ((size_t)(8  + nt) * 4 + ks) * 512 + l * 8);
            bf16x8 bhm = *(const bf16x8*)(wl + ((size_t)(16 + nt) * 4 + ks) * 512 + l * 8);
            bf16x8 blm = *(const bf16x8*)(wl + ((size_t)(24 + nt) * 4 + ks) * 512 + l * 8);
#pragma unroll
            for (int rf = 0; rf < 2; ++rf) {
                accq[rf][ntp] = __builtin_amdgcn_mfma_f32_16x16x32_bf16(Ah[rf][ks], bhq, accq[rf][ntp], 0, 0, 0);
                accq[rf][ntp] = __builtin_amdgcn_mfma_f32_16x16x32_bf16(Ah[rf][ks], blq, accq[rf][ntp], 0, 0, 0);
                accq[rf][ntp] = __builtin_amdgcn_mfma_f32_16x16x32_bf16(Al[rf][ks], bhq, accq[rf][ntp], 0, 0, 0);
                accm[rf][ntp] = __builtin_amdgcn_mfma_f32_16x16x32_bf16(Ah[rf][ks], bhm, accm[rf][ntp], 0, 0, 0);
                accm[rf][ntp] = __builtin_amdgcn_mfma_f32_16x16x32_bf16(Ah[rf][ks], blm, accm[rf][ntp], 0, 0, 0);
                accm[rf][ntp] = __builtin_amdgcn_mfma_f32_16x16x32_bf16(Al[rf][ks], bhm, accm[rf][ntp], 0, 0, 0);
            }
        }
    }
    float sq1[2][4] = {{0,0,0,0},{0,0,0,0}};
    float sq2[2][4] = {{0,0,0,0},{0,0,0,0}};
#pragma unroll
    for (int ntp = 0; ntp < 2; ++ntp) {
        int c = (w * 2 + ntp) * 16 + l15;
        float bqv = bq[c] + EPSF, bmv = bm[c];
#pragma unroll
        for (int rf = 0; rf < 2; ++rf)
#pragma unroll
            for (int reg = 0; reg < 4; ++reg) {
                int rloc = rf * 16 + g * 4 + reg;
                float qp = accq[rf][ntp][reg] + bqv;
                float mv = 1.0f / (1.0f + expf(-(accm[rf][ntp][reg] + bmv)));
                size_t o = (size_t)(row0 + rloc) * 128 + c;
                mq[o] = mv * qp;
                mo[o] = mv;
                sq1[rf][reg] += qp;
                sq2[rf][reg] += qp * qp;
            }
    }
#pragma unroll
    for (int rf = 0; rf < 2; ++rf)
#pragma unroll
        for (int reg = 0; reg < 4; ++reg) {
            float a = sq1[rf][reg], b = sq2[rf][reg];
            a += __shfl_xor(a, 1); a += __shfl_xor(a, 2);
            a += __shfl_xor(a, 4); a += __shfl_xor(a, 8);
            b += __shfl_xor(b, 1); b += __shfl_xor(b, 2);
            b += __shfl_xor(b, 4); b += __shfl_xor(b, 8);
            if (l15 == 0) {
                red[rf * 16 + g * 4 + reg][w][0] = a;
                red[rf * 16 + g * 4 + reg][w][1] = b;
            }
        }
    __syncthreads();
    if (t < 32) {
        float a = red[t][0][0] + red[t][1][0] + red[t][2][0] + red[t][3][0];
        float b = red[t][0][1] + red[t][1][1] + red[t][2][1] + red[t][3][1];
        scal[(size_t)(row0 + t) * 4 + 2] = a;
        scal[(size_t)(row0 + t) * 4 + 3] = sqrtf(b);
    }
}

// ---- K2: windowed pair loop -> qrh2. One row/block; 4 waves x 4 groups of
//      16 lanes = 16 dists per iteration; lane owns 8 d-elements.
__global__ __launch_bounds__(256) void k2_qr(
    const float* __restrict__ x,
    const float* __restrict__ mq, const float* __restrict__ mo,
    const float* __restrict__ scal, short* __restrict__ qrh2)
{
    int row = blockIdx.x;
    int i = row & (SS - 1);
    const float* xb = x + (size_t)(row - i) * DD;
    int t = threadIdx.x, w = t >> 6, l = t & 63;
    int sub = l >> 4, q = l & 15;
    int qo = q * 8;

    float mqv[8], mov[8];
    {
        const float* mp = mq + (size_t)row * DD + qo;
        float4 a = *(const float4*)mp, b = *(const float4*)(mp + 4);
        mqv[0] = a.x; mqv[1] = a.y; mqv[2] = a.z; mqv[3] = a.w;
        mqv[4] = b.x; mqv[5] = b.y; mqv[6] = b.z; mqv[7] = b.w;
        const float* op = mo + (size_t)row * DD + qo;
        float4 c = *(const float4*)op, d = *(const float4*)(op + 4);
        mov[0] = c.x; mov[1] = c.y; mov[2] = c.z; mov[3] = c.w;
        mov[4] = d.x; mov[5] = d.y; mov[6] = d.z; mov[7] = d.w;
    }
    float wv = scal[row * 4 + 0], cv = scal[row * 4 + 1];
    float sumqp = scal[row * 4 + 2], nb = scal[row * 4 + 3];
    float wi = wv + EPSF;
    float dmaxf = cv + TCUT * wi;
    int dmax = (dmaxf >= (float)i) ? i : (int)dmaxf;

    float acc[8] = {0.f, 0.f, 0.f, 0.f, 0.f, 0.f, 0.f, 0.f};
    int nit = (dmax + 15) >> 4;
    int dbase = 1 + w * 4 + sub;
    for (int it = 0; it < nit; ++it) {
        int dist = dbase + it * 16;
        float xv[8];
        if (dist <= dmax) {
            const float* xp = xb + (size_t)(i - dist) * DD + qo;
            float4 a = *(const float4*)xp, b = *(const float4*)(xp + 4);
            xv[0] = a.x; xv[1] = a.y; xv[2] = a.z; xv[3] = a.w;
            xv[4] = b.x; xv[5] = b.y; xv[6] = b.z; xv[7] = b.w;
        } else {
#pragma unroll
            for (int e = 0; e < 8; ++e) xv[e] = 0.f;
        }
        float t1 = 0.f, s1 = 0.f, s2 = 0.f;
#pragma unroll
        for (int e = 0; e < 8; ++e) {
            float xm = xv[e] * mov[e];
            t1 = fmaf(xv[e], mqv[e], t1);
            s1 += xm;
            s2 = fmaf(xm, xm, s2);
        }
#pragma unroll
        for (int off = 1; off < 16; off <<= 1) {
            t1 += __shfl_xor(t1, off);
            s1 += __shfl_xor(s1, off);
            s2 += __shfl_xor(s2, off);
        }
        float tt = ((float)dist - cv) / wi;
        float pe = 1.0f / coshf(tt);
        float dotv = fmaf(pe, t1, EPSF * sumqp);
        float na = sqrtf(fmaf(pe * pe, s2,
                         fmaf(2.0f * EPSF * pe, s1, (float)DD * EPSF * EPSF)));
        float cosv = fminf(1.0f, fmaxf(-1.0f, dotv / (na * nb)));
        float ang = acosf(cosv);
        float wgt = pe * ang;
#pragma unroll
        for (int e = 0; e < 8; ++e) acc[e] = fmaf(wgt, xv[e], acc[e]);
    }
#pragma unroll
    for (int e = 0; e < 8; ++e) {
        acc[e] += __shfl_xor(acc[e], 16);
        acc[e] += __shfl_xor(acc[e], 32);
    }
    __shared__ float sq[4][DD];
    if (l < 16) {
#pragma unroll
        for (int e = 0; e < 8; ++e) sq[w][qo + e] = acc[e];
    }
    __syncthreads();
    if (t < DD) {
        float v = sq[0][t] + sq[1][t] + sq[2][t] + sq[3][t];
        int rbq = row >> 7, rr = row & 127, rt2 = rr >> 5, lp = rr & 31;
        int k = t;
        qrh2[(((size_t)(rbq * 4 + rt2) * 8 + (k >> 4)) * 64
              + (lp + 32 * ((k >> 3) & 1))) * 8 + (k & 7)] = f2bf(v);
    }
}

// ---- K3: G-GEMM (32x32x16 MFMA), k-split waves, x-weighted epilogue --------
// grid (64 rb, 4 js), 512 thr (8 waves). Wave (kh = w&3, dh = w>>2) owns
// ks in {2kh, 2kh+1} and d in [dh*64, dh*64+64), computing ALL 4 row-tiles.
// Each A-fragment read by exactly one wave -> 1 MB L2 traffic per block
// (was 4 MB with row-split waves). kh partials combined via LDS atomicAdd
// (epilogue is linear in acc). Per-wave d-loop rotated by kh*16.
__global__ __launch_bounds__(512, 2) void k3_gemm(
    const float* __restrict__ x, const short* __restrict__ embh3,
    const short* __restrict__ qrh2, float* __restrict__ part)
{
    __shared__ float xt[32][132];                 // [j][r], padded
    __shared__ __align__(16) float sbuf[128][129];// [r][d], pad 129 -> ds_add conflict-free
    int t = threadIdx.x, w8 = t >> 6, l = t & 63;
    int l31 = l & 31, hi = l >> 5;
    int kh = w8 & 3, dh = w8 >> 2;
    int rb = blockIdx.x, js = blockIdx.y;

    // zero sbuf (atomic accumulation target)
    for (int idx = t; idx < 128 * 129; idx += 512) ((float*)sbuf)[idx] = 0.f;

    // stage xt[j][r] = x[(rb*128+r)*128 + js*32 + j]
    {
        int r = t & 127, jq = (t >> 7) * 8;
        const float* xp = x + (size_t)(rb * 128 + r) * 128 + js * 32 + jq;
        float4 a = *(const float4*)xp, b = *(const float4*)(xp + 4);
        xt[jq + 0][r] = a.x; xt[jq + 1][r] = a.y;
        xt[jq + 2][r] = a.z; xt[jq + 3][r] = a.w;
        xt[jq + 4][r] = b.x; xt[jq + 5][r] = b.y;
        xt[jq + 6][r] = b.z; xt[jq + 7][r] = b.w;
    }

    // B fragments: qr for all 4 row-tiles, own ks pair only (32 VGPR)
    bf16x8 Bf[4][2];
    const short* qb = qrh2 + (size_t)rb * 16384;
#pragma unroll
    for (int rt = 0; rt < 4; ++rt)
#pragma unroll
        for (int p = 0; p < 2; ++p)
            Bf[rt][p] = *(const bf16x8*)(qb + (size_t)((rt * 8 + 2 * kh + p) * 64 + l) * 8);

    __syncthreads();
    float xv[4][16];
#pragma unroll
    for (int rt = 0; rt < 4; ++rt)
#pragma unroll
        for (int reg = 0; reg < 16; ++reg) {
            int rowj = (reg & 3) + 8 * (reg >> 2) + 4 * hi;
            xv[rt][reg] = xt[rowj][rt * 32 + l31];
        }

    const int ibase = kh * 16;   // rotate d-start per kh wave
    const short* Abase = embh3 + (size_t)(dh * 256 + js) * 4096
                         + (size_t)(2 * kh) * 512 + (size_t)l * 8;

#define LOADA(AR, II)                                                        \
    {                                                                        \
        const short* ap_ = Abase + (size_t)((ibase + (II)) & 63) * 16384;    \
        AR[0] = *(const bf16x8*)(ap_);                                       \
        AR[1] = *(const bf16x8*)(ap_ + 512);                                 \
    }

#define COMPD(AR, II)                                                        \
    {                                                                        \
        int di_ = dh * 64 + ((ibase + (II)) & 63);                           \
        _Pragma("unroll")                                                    \
        for (int rt = 0; rt < 4; ++rt) {                                     \
            f32x16 acc;                                                      \
            _Pragma("unroll")                                                \
            for (int q = 0; q < 16; ++q) acc[q] = 0.f;                       \
            acc = __builtin_amdgcn_mfma_f32_32x32x16_bf16(AR[0], Bf[rt][0],  \
                                                          acc, 0, 0, 0);     \
            acc = __builtin_amdgcn_mfma_f32_32x32x16_bf16(AR[1], Bf[rt][1],  \
                                                          acc, 0, 0, 0);     \
            float s0 = 0.f, s1 = 0.f, s2 = 0.f, s3 = 0.f;                    \
            _Pragma("unroll")                                                \
            for (int q = 0; q < 4; ++q) {                                    \
                s0 = fmaf(xv[rt][q * 4 + 0], acc[q * 4 + 0], s0);            \
                s1 = fmaf(xv[rt][q * 4 + 1], acc[q * 4 + 1], s1);            \
                s2 = fmaf(xv[rt][q * 4 + 2], acc[q * 4 + 2], s2);            \
                s3 = fmaf(xv[rt][q * 4 + 3], acc[q * 4 + 3], s3);            \
            }                                                                \
            float s = (s0 + s1) + (s2 + s3);                                 \
            s += __shfl_xor(s, 32);                                          \
            if (hi == 0) atomicAdd(&sbuf[rt * 32 + l31][di_], s);            \
        }                                                                    \
    }

    bf16x8 Aa[2], Ab_[2], Ac_[2], Ad_[2];
    LOADA(Aa, 0) LOADA(Ab_, 1) LOADA(Ac_, 2) LOADA(Ad_, 3)

#pragma unroll 1
    for (int ii = 0; ii < 64; ii += 4) {
        COMPD(Aa, ii + 0)
        if (ii + 4 < 64) LOADA(Aa, ii + 4)
        COMPD(Ab_, ii + 1)
        if (ii + 5 < 64) LOADA(Ab_, ii + 5)
        COMPD(Ac_, ii + 2)
        if (ii + 6 < 64) LOADA(Ac_, ii + 6)
        COMPD(Ad_, ii + 3)
        if (ii + 7 < 64) LOADA(Ad_, ii + 7)
    }
#undef LOADA
#undef COMPD

    __syncthreads();
    // coalesced writeout (scalar LDS reads: 129-stride rows aren't 16B-aligned)
#pragma unroll
    for (int e = 0; e < 8; ++e) {
        int idx4 = e * 512 + t;
        int r = idx4 >> 5, c4 = (idx4 & 31) * 4;
        float4 v;
        v.x = sbuf[r][c4 + 0];
        v.y = sbuf[r][c4 + 1];
        v.z = sbuf[r][c4 + 2];
        v.w = sbuf[r][c4 + 3];
        *(float4*)(part + (size_t)js * (NROWS * DD)
                   + (size_t)(rb * 128 + r) * 128 + c4) = v;
    }
}

// ---- K4: sum partials + x, LayerNorm ---------------------------------------
__global__ __launch_bounds__(256) void k4_ln(
    const float* __restrict__ x, const float* __restrict__ part,
    const float* __restrict__ gamma, const float* __restrict__ beta,
    float* __restrict__ out)
{
    int wave = threadIdx.x >> 6, lane = threadIdx.x & 63;
    int row = blockIdx.x * 4 + wave;
    size_t base = (size_t)row * DD;
    float r0 = x[base + lane], r1 = x[base + lane + 64];
#pragma unroll
    for (int p = 0; p < 4; ++p) {
        r0 += part[(size_t)p * NROWS * DD + base + lane];
        r1 += part[(size_t)p * NROWS * DD + base + lane + 64];
    }
    float s = r0 + r1, s2 = r0 * r0 + r1 * r1;
#pragma unroll
    for (int off = 32; off > 0; off >>= 1) {
        s += __shfl_xor(s, off);
        s2 += __shfl_xor(s2, off);
    }
    float mu = s * (1.0f / DD);
    float var = s2 * (1.0f / DD) - mu * mu;
    var = fmaxf(var, 0.0f);
    float rs = rsqrtf(var + LN_EPSF);
    out[base + lane] = (r0 - mu) * rs * gamma[lane] + beta[lane];
    out[base + lane + 64] = (r1 - mu) * rs * gamma[lane + 64] + beta[lane + 64];
}

extern "C" void kernel_launch(void* const* d_in, const int* in_sizes, int n_in,
                              void* d_out, int out_size, void* d_ws, size_t ws_size,
                              hipStream_t stream) {
    const float* x     = (const float*)d_in[0];
    const float* Wq    = (const float*)d_in[1];
    const float* bq    = (const float*)d_in[2];
    const float* Wm    = (const float*)d_in[3];
    const float* bm    = (const float*)d_in[4];
    const float* Ww    = (const float*)d_in[5];
    const float* bw    = (const float*)d_in[6];
    const float* Wc    = (const float*)d_in[7];
    const float* bc    = (const float*)d_in[8];
    const float* emb   = (const float*)d_in[9];
    const float* gamma = (const float*)d_in[10];
    const float* beta  = (const float*)d_in[11];
    float* out = (float*)d_out;
    float* ws  = (float*)d_ws;

    short* embh3 = (short*)ws;                  // 4 MB
    short* qrh2  = (short*)(ws + 1048576);      // 2 MB
    float* scal  = ws + 1572864;
    float* part  = ws + 1605632;                // 16 MB
    short* xh2   = (short*)part;                // transients alias part
    short* xl2   = (short*)(part + 524288);
    float* mq    = part + 1048576;
    float* mo    = part + 2097152;
    short* Wfrag = (short*)(part + 3145728);

    hipLaunchKernelGGL(k0a_emb,   dim3(128, 4), dim3(256), 0, stream, emb, embh3);
    hipLaunchKernelGGL(k0w_split, dim3(256),    dim3(256), 0, stream, Wq, Wm, Wfrag);
    hipLaunchKernelGGL(k0c_xsplit,dim3(256),    dim3(256), 0, stream,
                       x, Ww, bw, Wc, bc, xh2, xl2, scal);
    hipLaunchKernelGGL(k1_mfma,   dim3(256),    dim3(256), 0, stream,
                       xh2, xl2, Wfrag, bq, bm, mq, mo, scal);
    hipLaunchKernelGGL(k2_qr,     dim3(8192),   dim3(256), 0, stream,
                       x, mq, mo, scal, qrh2);
    hipLaunchKernelGGL(k3_gemm,   dim3(64, 4),  dim3(512), 0, stream,
                       x, embh3, qrh2, part);
    hipLaunchKernelGGL(k4_ln,     dim3(2048),   dim3(256), 0, stream,
                       x, part, gamma, beta, out);
}

// Round 7
// 92.980 us; speedup vs baseline: 1.6439x; 1.6439x over previous
//
#include <hip/hip_runtime.h>
#include <hip/hip_bf16.h>
#include <math.h>

#define DD 128
#define SS 1024
#define NROWS 8192
#define EPSF 1e-7f
#define LN_EPSF 1e-3f
#define TCUT 30.0f

typedef __attribute__((ext_vector_type(8))) short bf16x8;
typedef __attribute__((ext_vector_type(4))) float f32x4;
typedef __attribute__((ext_vector_type(16))) float f32x16;

__device__ __forceinline__ void gload_lds16(const void* g, void* l) {
    __builtin_amdgcn_global_load_lds(
        (const __attribute__((address_space(1))) unsigned int*)g,
        (__attribute__((address_space(3))) unsigned int*)l, 16, 0, 0);
}
__device__ __forceinline__ short f2bf(float v) {
    union { __hip_bfloat16 h; short s; } u;
    u.h = __float2bfloat16(v);
    return u.s;
}
__device__ __forceinline__ float bf2f(short s) {
    union { __hip_bfloat16 h; short s; } u; u.s = s;
    return __bfloat162float(u.h);
}
__device__ __forceinline__ unsigned int pack_bf16(float lo, float hi) {
    unsigned int r;
    asm("v_cvt_pk_bf16_f32 %0, %1, %2" : "=v"(r) : "v"(lo), "v"(hi));
    return r;
}
__device__ __forceinline__ float u2f(unsigned int u) {
    union { unsigned int u; float f; } c; c.u = u; return c.f;
}

// ---- K0a: emb -> bf16 fragment-linear: embh3[(d*4+js)*4096 + (ks*64+l)*8+e]
//      = emb[d][js*32 + (l&31)][ks*16 + (l>>5)*8 + e]
__global__ __launch_bounds__(256) void k0a_emb(const float* __restrict__ emb,
                                               short* __restrict__ embh3) {
    __shared__ float lt[32][128];
    int d = blockIdx.x, js = blockIdx.y, t = threadIdx.x;
    {
        int jl = t >> 3, k0 = (t & 7) * 16;
        const float4* src = (const float4*)(emb + (size_t)d * 16384
                                            + (size_t)(js * 32 + jl) * 128 + k0);
#pragma unroll
        for (int q = 0; q < 4; ++q) *(float4*)&lt[jl][k0 + q * 4] = src[q];
    }
    __syncthreads();
    int ks = t >> 5, l0 = (t & 31) * 2;
    union { bf16x8 v[2]; short s[16]; } ob;
#pragma unroll
    for (int li = 0; li < 2; ++li) {
        int l = l0 + li;
        const float* p = &lt[l & 31][ks * 16 + (l >> 5) * 8];
#pragma unroll
        for (int e = 0; e < 8; ++e) ob.s[li * 8 + e] = f2bf(p[e]);
    }
    short* dst = embh3 + (size_t)(d * 4 + js) * 4096 + (size_t)t * 16;
    *(bf16x8*)dst = ob.v[0];
    *(bf16x8*)(dst + 8) = ob.v[1];
}

// ---- K0w: split Wq|Wm into bf16 hi/lo fragment-linear for k1 --------------
__global__ __launch_bounds__(256) void k0w_split(const float* __restrict__ Wq,
        const float* __restrict__ Wm, short* __restrict__ Wfrag) {
    int T = blockIdx.x * 256 + threadIdx.x;       // 65536 total
    int e = T & 7, l = (T >> 3) & 63, ks = (T >> 9) & 3, nt = (T >> 11) & 7,
        mat = (T >> 14) & 1;
    int k = ks * 32 + ((l >> 4) & 3) * 8 + e;
    int c = nt * 16 + (l & 15);
    float v = (mat ? Wm : Wq)[k * 128 + c];
    short h = f2bf(v);
    float lo = v - bf2f(h);
    Wfrag[((((size_t)(mat * 2 + 0) * 8 + nt) * 4 + ks) * 64 + l) * 8 + e] = h;
    Wfrag[((((size_t)(mat * 2 + 1) * 8 + nt) * 4 + ks) * 64 + l) * 8 + e] = f2bf(lo);
}

// ---- K0c: x -> xh2/xl2 (frag-linear for k1) + w,c scalars ------------------
__global__ __launch_bounds__(256) void k0c_xsplit(const float* __restrict__ x,
        const float* __restrict__ Ww, const float* __restrict__ bw,
        const float* __restrict__ Wc, const float* __restrict__ bc,
        short* __restrict__ xh2, short* __restrict__ xl2,
        float* __restrict__ scal) {
    __shared__ float xs[32][129];
    int rb = blockIdx.x, t = threadIdx.x;
    {
        int r = t >> 3, d0 = (t & 7) * 16;
        const float4* src = (const float4*)(x + (size_t)(rb * 32 + r) * 128 + d0);
#pragma unroll
        for (int q = 0; q < 4; ++q) *(float4*)&xs[r][d0 + q * 4] = src[q];
    }
    __syncthreads();
    int ks = (t >> 5) & 3, rf = t >> 7, l0 = (t & 31) * 2;
    union { bf16x8 v[2]; short s[16]; } hb, lb;
#pragma unroll
    for (int li = 0; li < 2; ++li) {
        int l = l0 + li;
        const float* p = &xs[rf * 16 + (l & 15)][ks * 32 + ((l >> 4) & 3) * 8];
#pragma unroll
        for (int e = 0; e < 8; ++e) {
            float v = p[e];
            short h = f2bf(v);
            hb.s[li * 8 + e] = h;
            lb.s[li * 8 + e] = f2bf(v - bf2f(h));
        }
    }
    {
        short* d1 = xh2 + (size_t)rb * 4096 + (size_t)t * 16;
        short* d2 = xl2 + (size_t)rb * 4096 + (size_t)t * 16;
        *(bf16x8*)d1 = hb.v[0]; *(bf16x8*)(d1 + 8) = hb.v[1];
        *(bf16x8*)d2 = lb.v[0]; *(bf16x8*)(d2 + 8) = lb.v[1];
    }
    // w, c scalars
    int rr = t >> 3, seg = t & 7;
    float pw = 0.f, pc = 0.f;
#pragma unroll
    for (int dq = 0; dq < 16; ++dq) {
        float xv = xs[rr][seg * 16 + dq];
        pw = fmaf(xv, Ww[seg * 16 + dq], pw);
        pc = fmaf(xv, Wc[seg * 16 + dq], pc);
    }
    pw += __shfl_xor(pw, 1); pw += __shfl_xor(pw, 2); pw += __shfl_xor(pw, 4);
    pc += __shfl_xor(pc, 1); pc += __shfl_xor(pc, 2); pc += __shfl_xor(pc, 4);
    if (seg == 0) {
        scal[(size_t)(rb * 32 + rr) * 4 + 0] = fmaxf(pw + bw[0], 0.f);
        scal[(size_t)(rb * 32 + rr) * 4 + 1] = fmaxf(pc + bc[0], 0.f);
    }
}

// ---- K1: q'/m via split-bf16 MFMA (3 products each), fused epilogue --------
__global__ __launch_bounds__(256) void k1_mfma(
    const short* __restrict__ xh2, const short* __restrict__ xl2,
    const short* __restrict__ Wfrag,
    const float* __restrict__ bq, const float* __restrict__ bm,
    float* __restrict__ mq, float* __restrict__ mo, float* __restrict__ scal)
{
    __shared__ __align__(16) short wl[65536];   // 128 KB
    __shared__ float red[32][4][2];
    int t = threadIdx.x, w = t >> 6, l = t & 63;
    int l15 = l & 15, g = l >> 4;
    int row0 = blockIdx.x * 32;
#pragma unroll
    for (int it = 0; it < 32; ++it)
        gload_lds16(Wfrag + (size_t)(it * 256 + t) * 8, wl + (size_t)(it * 256 + w * 64) * 8);
    const short* xb  = xh2 + (size_t)blockIdx.x * 4096;
    const short* xlb = xl2 + (size_t)blockIdx.x * 4096;
    bf16x8 Ah[2][4], Al[2][4];
#pragma unroll
    for (int rf = 0; rf < 2; ++rf)
#pragma unroll
        for (int ks = 0; ks < 4; ++ks) {
            size_t o = ((size_t)(rf * 4 + ks) * 64 + l) * 8;
            Ah[rf][ks] = *(const bf16x8*)(xb + o);
            Al[rf][ks] = *(const bf16x8*)(xlb + o);
        }
    __syncthreads();
    f32x4 accq[2][2] = {}, accm[2][2] = {};
#pragma unroll
    for (int ntp = 0; ntp < 2; ++ntp) {
        int nt = w * 2 + ntp;
#pragma unroll
        for (int ks = 0; ks < 4; ++ks) {
            bf16x8 bhq = *(const bf16x8*)(wl + ((size_t)(0  + nt) * 4 + ks) * 512 + l * 8);
            bf16x8 blq = *(const bf16x8*)(wl + ((size_t)(8  + nt) * 4 + ks) * 512 + l * 8);
            bf16x8 bhm = *(const bf16x8*)(wl + ((size_t)(16 + nt) * 4 + ks) * 512 + l * 8);
            bf16x8 blm = *(const bf16x8*)(wl + ((size_t)(24 + nt) * 4 + ks) * 512 + l * 8);
#pragma unroll
            for (int rf = 0; rf < 2; ++rf) {
                accq[rf][ntp] = __builtin_amdgcn_mfma_f32_16x16x32_bf16(Ah[rf][ks], bhq, accq[rf][ntp], 0, 0, 0);
                accq[rf][ntp] = __builtin_amdgcn_mfma_f32_16x16x32_bf16(Ah[rf][ks], blq, accq[rf][ntp], 0, 0, 0);
                accq[rf][ntp] = __builtin_amdgcn_mfma_f32_16x16x32_bf16(Al[rf][ks], bhq, accq[rf][ntp], 0, 0, 0);
                accm[rf][ntp] = __builtin_amdgcn_mfma_f32_16x16x32_bf16(Ah[rf][ks], bhm, accm[rf][ntp], 0, 0, 0);
                accm[rf][ntp] = __builtin_amdgcn_mfma_f32_16x16x32_bf16(Ah[rf][ks], blm, accm[rf][ntp], 0, 0, 0);
                accm[rf][ntp] = __builtin_amdgcn_mfma_f32_16x16x32_bf16(Al[rf][ks], bhm, accm[rf][ntp], 0, 0, 0);
            }
        }
    }
    float sq1[2][4] = {{0,0,0,0},{0,0,0,0}};
    float sq2[2][4] = {{0,0,0,0},{0,0,0,0}};
#pragma unroll
    for (int ntp = 0; ntp < 2; ++ntp) {
        int c = (w * 2 + ntp) * 16 + l15;
        float bqv = bq[c] + EPSF, bmv = bm[c];
#pragma unroll
        for (int rf = 0; rf < 2; ++rf)
#pragma unroll
            for (int reg = 0; reg < 4; ++reg) {
                int rloc = rf * 16 + g * 4 + reg;
                float qp = accq[rf][ntp][reg] + bqv;
                float mv = 1.0f / (1.0f + expf(-(accm[rf][ntp][reg] + bmv)));
                size_t o = (size_t)(row0 + rloc) * 128 + c;
                mq[o] = mv * qp;
                mo[o] = mv;
                sq1[rf][reg] += qp;
                sq2[rf][reg] += qp * qp;
            }
    }
#pragma unroll
    for (int rf = 0; rf < 2; ++rf)
#pragma unroll
        for (int reg = 0; reg < 4; ++reg) {
            float a = sq1[rf][reg], b = sq2[rf][reg];
            a += __shfl_xor(a, 1); a += __shfl_xor(a, 2);
            a += __shfl_xor(a, 4); a += __shfl_xor(a, 8);
            b += __shfl_xor(b, 1); b += __shfl_xor(b, 2);
            b += __shfl_xor(b, 4); b += __shfl_xor(b, 8);
            if (l15 == 0) {
                red[rf * 16 + g * 4 + reg][w][0] = a;
                red[rf * 16 + g * 4 + reg][w][1] = b;
            }
        }
    __syncthreads();
    if (t < 32) {
        float a = red[t][0][0] + red[t][1][0] + red[t][2][0] + red[t][3][0];
        float b = red[t][0][1] + red[t][1][1] + red[t][2][1] + red[t][3][1];
        scal[(size_t)(row0 + t) * 4 + 2] = a;
        scal[(size_t)(row0 + t) * 4 + 3] = sqrtf(b);
    }
}

// ---- K2: windowed pair loop -> qrh2. One row/block; 4 waves x 4 groups of
//      16 lanes = 16 dists per iteration; lane owns 8 d-elements.
__global__ __launch_bounds__(256) void k2_qr(
    const float* __restrict__ x,
    const float* __restrict__ mq, const float* __restrict__ mo,
    const float* __restrict__ scal, short* __restrict__ qrh2)
{
    int row = blockIdx.x;
    int i = row & (SS - 1);
    const float* xb = x + (size_t)(row - i) * DD;
    int t = threadIdx.x, w = t >> 6, l = t & 63;
    int sub = l >> 4, q = l & 15;
    int qo = q * 8;

    float mqv[8], mov[8];
    {
        const float* mp = mq + (size_t)row * DD + qo;
        float4 a = *(const float4*)mp, b = *(const float4*)(mp + 4);
        mqv[0] = a.x; mqv[1] = a.y; mqv[2] = a.z; mqv[3] = a.w;
        mqv[4] = b.x; mqv[5] = b.y; mqv[6] = b.z; mqv[7] = b.w;
        const float* op = mo + (size_t)row * DD + qo;
        float4 c = *(const float4*)op, d = *(const float4*)(op + 4);
        mov[0] = c.x; mov[1] = c.y; mov[2] = c.z; mov[3] = c.w;
        mov[4] = d.x; mov[5] = d.y; mov[6] = d.z; mov[7] = d.w;
    }
    float wv = scal[row * 4 + 0], cv = scal[row * 4 + 1];
    float sumqp = scal[row * 4 + 2], nb = scal[row * 4 + 3];
    float wi = wv + EPSF;
    float dmaxf = cv + TCUT * wi;
    int dmax = (dmaxf >= (float)i) ? i : (int)dmaxf;

    float acc[8] = {0.f, 0.f, 0.f, 0.f, 0.f, 0.f, 0.f, 0.f};
    int nit = (dmax + 15) >> 4;
    int dbase = 1 + w * 4 + sub;
    for (int it = 0; it < nit; ++it) {
        int dist = dbase + it * 16;
        float xv[8];
        if (dist <= dmax) {
            const float* xp = xb + (size_t)(i - dist) * DD + qo;
            float4 a = *(const float4*)xp, b = *(const float4*)(xp + 4);
            xv[0] = a.x; xv[1] = a.y; xv[2] = a.z; xv[3] = a.w;
            xv[4] = b.x; xv[5] = b.y; xv[6] = b.z; xv[7] = b.w;
        } else {
#pragma unroll
            for (int e = 0; e < 8; ++e) xv[e] = 0.f;
        }
        float t1 = 0.f, s1 = 0.f, s2 = 0.f;
#pragma unroll
        for (int e = 0; e < 8; ++e) {
            float xm = xv[e] * mov[e];
            t1 = fmaf(xv[e], mqv[e], t1);
            s1 += xm;
            s2 = fmaf(xm, xm, s2);
        }
#pragma unroll
        for (int off = 1; off < 16; off <<= 1) {
            t1 += __shfl_xor(t1, off);
            s1 += __shfl_xor(s1, off);
            s2 += __shfl_xor(s2, off);
        }
        float tt = ((float)dist - cv) / wi;
        float pe = 1.0f / coshf(tt);
        float dotv = fmaf(pe, t1, EPSF * sumqp);
        float na = sqrtf(fmaf(pe * pe, s2,
                         fmaf(2.0f * EPSF * pe, s1, (float)DD * EPSF * EPSF)));
        float cosv = fminf(1.0f, fmaxf(-1.0f, dotv / (na * nb)));
        float ang = acosf(cosv);
        float wgt = pe * ang;
#pragma unroll
        for (int e = 0; e < 8; ++e) acc[e] = fmaf(wgt, xv[e], acc[e]);
    }
#pragma unroll
    for (int e = 0; e < 8; ++e) {
        acc[e] += __shfl_xor(acc[e], 16);
        acc[e] += __shfl_xor(acc[e], 32);
    }
    __shared__ float sq[4][DD];
    if (l < 16) {
#pragma unroll
        for (int e = 0; e < 8; ++e) sq[w][qo + e] = acc[e];
    }
    __syncthreads();
    if (t < DD) {
        float v = sq[0][t] + sq[1][t] + sq[2][t] + sq[3][t];
        int rbq = row >> 7, rr = row & 127, rt2 = rr >> 5, lp = rr & 31;
        int k = t;
        qrh2[(((size_t)(rbq * 4 + rt2) * 8 + (k >> 4)) * 64
              + (lp + 32 * ((k >> 3) & 1))) * 8 + (k & 7)] = f2bf(v);
    }
}

// ---- K3: G-GEMM (32x32x16 MFMA), LDS-staged emb tile, kp-split partials ----
// grid (rc=16, dq=16, js=4), 512 thr (8 waves). Block: 512 rows x 8 d x 32 j.
// Wave (kp = w&1, rh = w>>1): K-half kp, rows [rh*128, rh*128+128) (4 rt).
// emb tile (8d x 32j x 128k = 64 KB bf16) staged ONCE via global_load_lds ->
// L2 traffic 64 MB total (was 1 GB). kp-partials NOT combined on-chip:
// written as separate bf16 planes (8 = js*2), summed in k4. No atomics.
__global__ __launch_bounds__(512, 2) void k3_gemm(
    const float* __restrict__ x, const short* __restrict__ embh3,
    const short* __restrict__ qrh2, short* __restrict__ partb)
{
    __shared__ __align__(16) char ldsb[81920];      // 80 KB -> 2 blocks/CU
    short* xtwh = (short*)ldsb;                     // phase1: [512][36] bf16 (36 KB)
    short* elds = (short*)ldsb;                     // phase2: [8][4096] bf16 (64 KB)
    short* swb  = (short*)(ldsb + 65536);           // phase3: [2][512][8] bf16 (16 KB)

    int t = threadIdx.x, w8 = t >> 6, l = t & 63;
    int l31 = l & 31, hi = l >> 5;
    int kp = w8 & 1, rh = w8 >> 1;
    int rc = blockIdx.x, dq = blockIdx.y, js = blockIdx.z;

    // phase 1: stage x tile (512 r x 32 j) as bf16 into xtwh[r][36]
#pragma unroll
    for (int i = 0; i < 8; ++i) {
        int idx = i * 512 + t;
        int r = idx >> 3, j4 = (idx & 7) * 4;
        float4 v = *(const float4*)(x + (size_t)(rc * 512 + r) * 128 + js * 32 + j4);
        *(unsigned int*)(xtwh + r * 36 + j4)     = pack_bf16(v.x, v.y);
        *(unsigned int*)(xtwh + r * 36 + j4 + 2) = pack_bf16(v.z, v.w);
    }

    // B fragments: own kp half of K, all 4 rt (64 VGPR)
    bf16x8 Bf[4][4];
    int rbq = rc * 4 + rh;
#pragma unroll
    for (int rt = 0; rt < 4; ++rt)
#pragma unroll
        for (int s = 0; s < 4; ++s)
            Bf[rt][s] = *(const bf16x8*)(qrh2
                + (((size_t)(rbq * 4 + rt) * 8 + kp * 4 + s) * 64 + l) * 8);

    __syncthreads();

    // extract xv (f32, 64 VGPR): xv[rt][reg] matches acc reg->j mapping
    float xv[4][16];
#pragma unroll
    for (int rt = 0; rt < 4; ++rt) {
        int row_l = rh * 128 + rt * 32 + l31;
#pragma unroll
        for (int p = 0; p < 8; ++p) {
            int jA = ((2 * p) & 3) + 8 * (p >> 1) + 4 * hi;
            unsigned int u = *(const unsigned int*)(xtwh + row_l * 36 + jA);
            xv[rt][2 * p]     = u2f(u << 16);
            xv[rt][2 * p + 1] = u2f(u & 0xFFFF0000u);
        }
    }

    __syncthreads();   // xtwh dead; overwrite with elds

    // phase 2: stage emb tile (64 KB) via global_load_lds
#pragma unroll
    for (int i = 0; i < 8; ++i) {
        int c = i * 512 + t;
        int d = c >> 9, off = c & 511;
        gload_lds16(embh3 + (size_t)((dq * 8 + d) * 4 + js) * 4096 + (size_t)off * 8,
                    elds + (size_t)(i * 512 + w8 * 64) * 8);
    }
    __syncthreads();

    float sprev[4];
    short* swbase = swb + (kp * 512 + rh * 128 + l31) * 8;

#define K3_DSTEP(DI, ODD)                                                    \
    {                                                                        \
        bf16x8 A[4];                                                         \
        _Pragma("unroll")                                                    \
        for (int s = 0; s < 4; ++s)                                          \
            A[s] = *(const bf16x8*)(elds + (DI) * 4096                       \
                                    + ((kp * 4 + s) * 64 + l) * 8);          \
        _Pragma("unroll")                                                    \
        for (int rtp = 0; rtp < 2; ++rtp) {                                  \
            f32x16 ac0, ac1;                                                 \
            _Pragma("unroll")                                                \
            for (int q = 0; q < 16; ++q) { ac0[q] = 0.f; ac1[q] = 0.f; }     \
            _Pragma("unroll")                                                \
            for (int s = 0; s < 4; ++s) {                                    \
                ac0 = __builtin_amdgcn_mfma_f32_32x32x16_bf16(               \
                    A[s], Bf[rtp * 2][s], ac0, 0, 0, 0);                     \
                ac1 = __builtin_amdgcn_mfma_f32_32x32x16_bf16(               \
                    A[s], Bf[rtp * 2 + 1][s], ac1, 0, 0, 0);                 \
            }                                                                \
            float sm0 = 0.f, sm1 = 0.f;                                      \
            _Pragma("unroll")                                                \
            for (int q = 0; q < 16; ++q) {                                   \
                sm0 = fmaf(xv[rtp * 2][q], ac0[q], sm0);                     \
                sm1 = fmaf(xv[rtp * 2 + 1][q], ac1[q], sm1);                 \
            }                                                                \
            sm0 += __shfl_xor(sm0, 32);                                      \
            sm1 += __shfl_xor(sm1, 32);                                      \
            if (ODD) {                                                       \
                if (hi == 0) {                                               \
                    *(unsigned int*)(swbase + rtp * 2 * 32 * 8 + (DI) - 1)   \
                        = pack_bf16(sprev[rtp * 2], sm0);                    \
                    *(unsigned int*)(swbase + (rtp * 2 + 1) * 32 * 8 + (DI) - 1) \
                        = pack_bf16(sprev[rtp * 2 + 1], sm1);                \
                }                                                            \
            } else {                                                         \
                sprev[rtp * 2] = sm0;                                        \
                sprev[rtp * 2 + 1] = sm1;                                    \
            }                                                                \
        }                                                                    \
    }

#pragma unroll
    for (int dp = 0; dp < 4; ++dp) {
        K3_DSTEP(2 * dp, 0)
        K3_DSTEP(2 * dp + 1, 1)
    }
#undef K3_DSTEP

    __syncthreads();
    // coalesced writeout: 16 KB -> partb plane (js*2+kp)
#pragma unroll
    for (int i = 0; i < 2; ++i) {
        int c = i * 512 + t;
        int kp2 = c >> 9, rl = c & 511;
        *(bf16x8*)(partb + (size_t)(js * 2 + kp2) * 1048576
                   + (size_t)(rc * 512 + rl) * 128 + dq * 8)
            = *(const bf16x8*)(swb + (kp2 * 512 + rl) * 8);
    }
}

// ---- K4: sum 8 bf16 partials + x, LayerNorm --------------------------------
__global__ __launch_bounds__(256) void k4_ln(
    const float* __restrict__ x, const short* __restrict__ partb,
    const float* __restrict__ gamma, const float* __restrict__ beta,
    float* __restrict__ out)
{
    int wave = threadIdx.x >> 6, lane = threadIdx.x & 63;
    int row = blockIdx.x * 4 + wave;
    size_t base = (size_t)row * DD;
    float r0 = x[base + lane], r1 = x[base + lane + 64];
#pragma unroll
    for (int p = 0; p < 8; ++p) {
        r0 += bf2f(partb[(size_t)p * 1048576 + base + lane]);
        r1 += bf2f(partb[(size_t)p * 1048576 + base + lane + 64]);
    }
    float s = r0 + r1, s2 = r0 * r0 + r1 * r1;
#pragma unroll
    for (int off = 32; off > 0; off >>= 1) {
        s += __shfl_xor(s, off);
        s2 += __shfl_xor(s2, off);
    }
    float mu = s * (1.0f / DD);
    float var = s2 * (1.0f / DD) - mu * mu;
    var = fmaxf(var, 0.0f);
    float rs = rsqrtf(var + LN_EPSF);
    out[base + lane] = (r0 - mu) * rs * gamma[lane] + beta[lane];
    out[base + lane + 64] = (r1 - mu) * rs * gamma[lane + 64] + beta[lane + 64];
}

extern "C" void kernel_launch(void* const* d_in, const int* in_sizes, int n_in,
                              void* d_out, int out_size, void* d_ws, size_t ws_size,
                              hipStream_t stream) {
    const float* x     = (const float*)d_in[0];
    const float* Wq    = (const float*)d_in[1];
    const float* bq    = (const float*)d_in[2];
    const float* Wm    = (const float*)d_in[3];
    const float* bm    = (const float*)d_in[4];
    const float* Ww    = (const float*)d_in[5];
    const float* bw    = (const float*)d_in[6];
    const float* Wc    = (const float*)d_in[7];
    const float* bc    = (const float*)d_in[8];
    const float* emb   = (const float*)d_in[9];
    const float* gamma = (const float*)d_in[10];
    const float* beta  = (const float*)d_in[11];
    float* out = (float*)d_out;
    float* ws  = (float*)d_ws;

    short* embh3 = (short*)ws;                  // 4 MB
    short* qrh2  = (short*)(ws + 1048576);      // 2 MB
    float* scal  = ws + 1572864;
    short* partb = (short*)(ws + 1605632);      // 16 MB (8 bf16 planes)
    float* tr    = ws + 1605632;                // transients alias partb
    short* xh2   = (short*)tr;
    short* xl2   = (short*)(tr + 524288);
    float* mq    = tr + 1048576;
    float* mo    = tr + 2097152;
    short* Wfrag = (short*)(tr + 3145728);

    hipLaunchKernelGGL(k0a_emb,   dim3(128, 4), dim3(256), 0, stream, emb, embh3);
    hipLaunchKernelGGL(k0w_split, dim3(256),    dim3(256), 0, stream, Wq, Wm, Wfrag);
    hipLaunchKernelGGL(k0c_xsplit,dim3(256),    dim3(256), 0, stream,
                       x, Ww, bw, Wc, bc, xh2, xl2, scal);
    hipLaunchKernelGGL(k1_mfma,   dim3(256),    dim3(256), 0, stream,
                       xh2, xl2, Wfrag, bq, bm, mq, mo, scal);
    hipLaunchKernelGGL(k2_qr,     dim3(8192),   dim3(256), 0, stream,
                       x, mq, mo, scal, qrh2);
    hipLaunchKernelGGL(k3_gemm,   dim3(16, 16, 4), dim3(512), 0, stream,
                       x, embh3, qrh2, partb);
    hipLaunchKernelGGL(k4_ln,     dim3(2048),   dim3(256), 0, stream,
                       x, partb, gamma, beta, out);
}

// Round 8
// 90.872 us; speedup vs baseline: 1.6820x; 1.0232x over previous
//
#include <hip/hip_runtime.h>
#include <hip/hip_bf16.h>
#include <math.h>

#define DD 128
#define SS 1024
#define NROWS 8192
#define EPSF 1e-7f
#define LN_EPSF 1e-3f
#define TCUT 30.0f

typedef __attribute__((ext_vector_type(8))) short bf16x8;
typedef __attribute__((ext_vector_type(4))) float f32x4;
typedef __attribute__((ext_vector_type(16))) float f32x16;

__device__ __forceinline__ void gload_lds16(const void* g, void* l) {
    __builtin_amdgcn_global_load_lds(
        (const __attribute__((address_space(1))) unsigned int*)g,
        (__attribute__((address_space(3))) unsigned int*)l, 16, 0, 0);
}
__device__ __forceinline__ short f2bf(float v) {
    union { __hip_bfloat16 h; short s; } u;
    u.h = __float2bfloat16(v);
    return u.s;
}
__device__ __forceinline__ float bf2f(short s) {
    union { __hip_bfloat16 h; short s; } u; u.s = s;
    return __bfloat162float(u.h);
}
__device__ __forceinline__ unsigned int pack_bf16(float lo, float hi) {
    unsigned int r;
    asm("v_cvt_pk_bf16_f32 %0, %1, %2" : "=v"(r) : "v"(lo), "v"(hi));
    return r;
}
__device__ __forceinline__ float u2f(unsigned int u) {
    union { unsigned int u; float f; } c; c.u = u; return c.f;
}

// ---- K0a: emb -> bf16 fragment-linear: embh3[(d*4+js)*4096 + (ks*64+l)*8+e]
//      = emb[d][js*32 + (l&31)][ks*16 + (l>>5)*8 + e]
__global__ __launch_bounds__(256) void k0a_emb(const float* __restrict__ emb,
                                               short* __restrict__ embh3) {
    __shared__ float lt[32][128];
    int d = blockIdx.x, js = blockIdx.y, t = threadIdx.x;
    {
        int jl = t >> 3, k0 = (t & 7) * 16;
        const float4* src = (const float4*)(emb + (size_t)d * 16384
                                            + (size_t)(js * 32 + jl) * 128 + k0);
#pragma unroll
        for (int q = 0; q < 4; ++q) *(float4*)&lt[jl][k0 + q * 4] = src[q];
    }
    __syncthreads();
    int ks = t >> 5, l0 = (t & 31) * 2;
    union { bf16x8 v[2]; short s[16]; } ob;
#pragma unroll
    for (int li = 0; li < 2; ++li) {
        int l = l0 + li;
        const float* p = &lt[l & 31][ks * 16 + (l >> 5) * 8];
#pragma unroll
        for (int e = 0; e < 8; ++e) ob.s[li * 8 + e] = f2bf(p[e]);
    }
    short* dst = embh3 + (size_t)(d * 4 + js) * 4096 + (size_t)t * 16;
    *(bf16x8*)dst = ob.v[0];
    *(bf16x8*)(dst + 8) = ob.v[1];
}

// ---- K0w: split Wq|Wm into bf16 hi/lo fragment-linear for k1 --------------
__global__ __launch_bounds__(256) void k0w_split(const float* __restrict__ Wq,
        const float* __restrict__ Wm, short* __restrict__ Wfrag) {
    int T = blockIdx.x * 256 + threadIdx.x;       // 65536 total
    int e = T & 7, l = (T >> 3) & 63, ks = (T >> 9) & 3, nt = (T >> 11) & 7,
        mat = (T >> 14) & 1;
    int k = ks * 32 + ((l >> 4) & 3) * 8 + e;
    int c = nt * 16 + (l & 15);
    float v = (mat ? Wm : Wq)[k * 128 + c];
    short h = f2bf(v);
    float lo = v - bf2f(h);
    Wfrag[((((size_t)(mat * 2 + 0) * 8 + nt) * 4 + ks) * 64 + l) * 8 + e] = h;
    Wfrag[((((size_t)(mat * 2 + 1) * 8 + nt) * 4 + ks) * 64 + l) * 8 + e] = f2bf(lo);
}

// ---- K0c: x -> xh2/xl2 (frag-linear for k1) + w,c scalars ------------------
__global__ __launch_bounds__(256) void k0c_xsplit(const float* __restrict__ x,
        const float* __restrict__ Ww, const float* __restrict__ bw,
        const float* __restrict__ Wc, const float* __restrict__ bc,
        short* __restrict__ xh2, short* __restrict__ xl2,
        float* __restrict__ scal) {
    __shared__ float xs[32][129];
    int rb = blockIdx.x, t = threadIdx.x;
    {
        int r = t >> 3, d0 = (t & 7) * 16;
        const float4* src = (const float4*)(x + (size_t)(rb * 32 + r) * 128 + d0);
#pragma unroll
        for (int q = 0; q < 4; ++q) *(float4*)&xs[r][d0 + q * 4] = src[q];
    }
    __syncthreads();
    int ks = (t >> 5) & 3, rf = t >> 7, l0 = (t & 31) * 2;
    union { bf16x8 v[2]; short s[16]; } hb, lb;
#pragma unroll
    for (int li = 0; li < 2; ++li) {
        int l = l0 + li;
        const float* p = &xs[rf * 16 + (l & 15)][ks * 32 + ((l >> 4) & 3) * 8];
#pragma unroll
        for (int e = 0; e < 8; ++e) {
            float v = p[e];
            short h = f2bf(v);
            hb.s[li * 8 + e] = h;
            lb.s[li * 8 + e] = f2bf(v - bf2f(h));
        }
    }
    {
        short* d1 = xh2 + (size_t)rb * 4096 + (size_t)t * 16;
        short* d2 = xl2 + (size_t)rb * 4096 + (size_t)t * 16;
        *(bf16x8*)d1 = hb.v[0]; *(bf16x8*)(d1 + 8) = hb.v[1];
        *(bf16x8*)d2 = lb.v[0]; *(bf16x8*)(d2 + 8) = lb.v[1];
    }
    // w, c scalars
    int rr = t >> 3, seg = t & 7;
    float pw = 0.f, pc = 0.f;
#pragma unroll
    for (int dq = 0; dq < 16; ++dq) {
        float xv = xs[rr][seg * 16 + dq];
        pw = fmaf(xv, Ww[seg * 16 + dq], pw);
        pc = fmaf(xv, Wc[seg * 16 + dq], pc);
    }
    pw += __shfl_xor(pw, 1); pw += __shfl_xor(pw, 2); pw += __shfl_xor(pw, 4);
    pc += __shfl_xor(pc, 1); pc += __shfl_xor(pc, 2); pc += __shfl_xor(pc, 4);
    if (seg == 0) {
        scal[(size_t)(rb * 32 + rr) * 4 + 0] = fmaxf(pw + bw[0], 0.f);
        scal[(size_t)(rb * 32 + rr) * 4 + 1] = fmaxf(pc + bc[0], 0.f);
    }
}

// ---- K1: q'/m via split-bf16 MFMA (3 products each), fused epilogue --------
__global__ __launch_bounds__(256) void k1_mfma(
    const short* __restrict__ xh2, const short* __restrict__ xl2,
    const short* __restrict__ Wfrag,
    const float* __restrict__ bq, const float* __restrict__ bm,
    float* __restrict__ mq, float* __restrict__ mo, float* __restrict__ scal)
{
    __shared__ __align__(16) short wl[65536];   // 128 KB
    __shared__ float red[32][4][2];
    int t = threadIdx.x, w = t >> 6, l = t & 63;
    int l15 = l & 15, g = l >> 4;
    int row0 = blockIdx.x * 32;
#pragma unroll
    for (int it = 0; it < 32; ++it)
        gload_lds16(Wfrag + (size_t)(it * 256 + t) * 8, wl + (size_t)(it * 256 + w * 64) * 8);
    const short* xb  = xh2 + (size_t)blockIdx.x * 4096;
    const short* xlb = xl2 + (size_t)blockIdx.x * 4096;
    bf16x8 Ah[2][4], Al[2][4];
#pragma unroll
    for (int rf = 0; rf < 2; ++rf)
#pragma unroll
        for (int ks = 0; ks < 4; ++ks) {
            size_t o = ((size_t)(rf * 4 + ks) * 64 + l) * 8;
            Ah[rf][ks] = *(const bf16x8*)(xb + o);
            Al[rf][ks] = *(const bf16x8*)(xlb + o);
        }
    __syncthreads();
    f32x4 accq[2][2] = {}, accm[2][2] = {};
#pragma unroll
    for (int ntp = 0; ntp < 2; ++ntp) {
        int nt = w * 2 + ntp;
#pragma unroll
        for (int ks = 0; ks < 4; ++ks) {
            bf16x8 bhq = *(const bf16x8*)(wl + ((size_t)(0  + nt) * 4 + ks) * 512 + l * 8);
            bf16x8 blq = *(const bf16x8*)(wl + ((size_t)(8  + nt) * 4 + ks) * 512 + l * 8);
            bf16x8 bhm = *(const bf16x8*)(wl + ((size_t)(16 + nt) * 4 + ks) * 512 + l * 8);
            bf16x8 blm = *(const bf16x8*)(wl + ((size_t)(24 + nt) * 4 + ks) * 512 + l * 8);
#pragma unroll
            for (int rf = 0; rf < 2; ++rf) {
                accq[rf][ntp] = __builtin_amdgcn_mfma_f32_16x16x32_bf16(Ah[rf][ks], bhq, accq[rf][ntp], 0, 0, 0);
                accq[rf][ntp] = __builtin_amdgcn_mfma_f32_16x16x32_bf16(Ah[rf][ks], blq, accq[rf][ntp], 0, 0, 0);
                accq[rf][ntp] = __builtin_amdgcn_mfma_f32_16x16x32_bf16(Al[rf][ks], bhq, accq[rf][ntp], 0, 0, 0);
                accm[rf][ntp] = __builtin_amdgcn_mfma_f32_16x16x32_bf16(Ah[rf][ks], bhm, accm[rf][ntp], 0, 0, 0);
                accm[rf][ntp] = __builtin_amdgcn_mfma_f32_16x16x32_bf16(Ah[rf][ks], blm, accm[rf][ntp], 0, 0, 0);
                accm[rf][ntp] = __builtin_amdgcn_mfma_f32_16x16x32_bf16(Al[rf][ks], bhm, accm[rf][ntp], 0, 0, 0);
            }
        }
    }
    float sq1[2][4] = {{0,0,0,0},{0,0,0,0}};
    float sq2[2][4] = {{0,0,0,0},{0,0,0,0}};
#pragma unroll
    for (int ntp = 0; ntp < 2; ++ntp) {
        int c = (w * 2 + ntp) * 16 + l15;
        float bqv = bq[c] + EPSF, bmv = bm[c];
#pragma unroll
        for (int rf = 0; rf < 2; ++rf)
#pragma unroll
            for (int reg = 0; reg < 4; ++reg) {
                int rloc = rf * 16 + g * 4 + reg;
                float qp = accq[rf][ntp][reg] + bqv;
                float mv = 1.0f / (1.0f + expf(-(accm[rf][ntp][reg] + bmv)));
                size_t o = (size_t)(row0 + rloc) * 128 + c;
                mq[o] = mv * qp;
                mo[o] = mv;
                sq1[rf][reg] += qp;
                sq2[rf][reg] += qp * qp;
            }
    }
#pragma unroll
    for (int rf = 0; rf < 2; ++rf)
#pragma unroll
        for (int reg = 0; reg < 4; ++reg) {
            float a = sq1[rf][reg], b = sq2[rf][reg];
            a += __shfl_xor(a, 1); a += __shfl_xor(a, 2);
            a += __shfl_xor(a, 4); a += __shfl_xor(a, 8);
            b += __shfl_xor(b, 1); b += __shfl_xor(b, 2);
            b += __shfl_xor(b, 4); b += __shfl_xor(b, 8);
            if (l15 == 0) {
                red[rf * 16 + g * 4 + reg][w][0] = a;
                red[rf * 16 + g * 4 + reg][w][1] = b;
            }
        }
    __syncthreads();
    if (t < 32) {
        float a = red[t][0][0] + red[t][1][0] + red[t][2][0] + red[t][3][0];
        float b = red[t][0][1] + red[t][1][1] + red[t][2][1] + red[t][3][1];
        scal[(size_t)(row0 + t) * 4 + 2] = a;
        scal[(size_t)(row0 + t) * 4 + 3] = sqrtf(b);
    }
}

// ---- K2: windowed pair loop -> qrh2. One row/block; 4 waves x 4 groups of
//      16 lanes = 16 dists per iteration; lane owns 8 d-elements.
__global__ __launch_bounds__(256) void k2_qr(
    const float* __restrict__ x,
    const float* __restrict__ mq, const float* __restrict__ mo,
    const float* __restrict__ scal, short* __restrict__ qrh2)
{
    int row = blockIdx.x;
    int i = row & (SS - 1);
    const float* xb = x + (size_t)(row - i) * DD;
    int t = threadIdx.x, w = t >> 6, l = t & 63;
    int sub = l >> 4, q = l & 15;
    int qo = q * 8;

    float mqv[8], mov[8];
    {
        const float* mp = mq + (size_t)row * DD + qo;
        float4 a = *(const float4*)mp, b = *(const float4*)(mp + 4);
        mqv[0] = a.x; mqv[1] = a.y; mqv[2] = a.z; mqv[3] = a.w;
        mqv[4] = b.x; mqv[5] = b.y; mqv[6] = b.z; mqv[7] = b.w;
        const float* op = mo + (size_t)row * DD + qo;
        float4 c = *(const float4*)op, d = *(const float4*)(op + 4);
        mov[0] = c.x; mov[1] = c.y; mov[2] = c.z; mov[3] = c.w;
        mov[4] = d.x; mov[5] = d.y; mov[6] = d.z; mov[7] = d.w;
    }
    float wv = scal[row * 4 + 0], cv = scal[row * 4 + 1];
    float sumqp = scal[row * 4 + 2], nb = scal[row * 4 + 3];
    float wi = wv + EPSF;
    float dmaxf = cv + TCUT * wi;
    int dmax = (dmaxf >= (float)i) ? i : (int)dmaxf;

    float acc[8] = {0.f, 0.f, 0.f, 0.f, 0.f, 0.f, 0.f, 0.f};
    int nit = (dmax + 15) >> 4;
    int dbase = 1 + w * 4 + sub;
    for (int it = 0; it < nit; ++it) {
        int dist = dbase + it * 16;
        float xv[8];
        if (dist <= dmax) {
            const float* xp = xb + (size_t)(i - dist) * DD + qo;
            float4 a = *(const float4*)xp, b = *(const float4*)(xp + 4);
            xv[0] = a.x; xv[1] = a.y; xv[2] = a.z; xv[3] = a.w;
            xv[4] = b.x; xv[5] = b.y; xv[6] = b.z; xv[7] = b.w;
        } else {
#pragma unroll
            for (int e = 0; e < 8; ++e) xv[e] = 0.f;
        }
        float t1 = 0.f, s1 = 0.f, s2 = 0.f;
#pragma unroll
        for (int e = 0; e < 8; ++e) {
            float xm = xv[e] * mov[e];
            t1 = fmaf(xv[e], mqv[e], t1);
            s1 += xm;
            s2 = fmaf(xm, xm, s2);
        }
#pragma unroll
        for (int off = 1; off < 16; off <<= 1) {
            t1 += __shfl_xor(t1, off);
            s1 += __shfl_xor(s1, off);
            s2 += __shfl_xor(s2, off);
        }
        float tt = ((float)dist - cv) / wi;
        float pe = 1.0f / coshf(tt);
        float dotv = fmaf(pe, t1, EPSF * sumqp);
        float na = sqrtf(fmaf(pe * pe, s2,
                         fmaf(2.0f * EPSF * pe, s1, (float)DD * EPSF * EPSF)));
        float cosv = fminf(1.0f, fmaxf(-1.0f, dotv / (na * nb)));
        float ang = acosf(cosv);
        float wgt = pe * ang;
#pragma unroll
        for (int e = 0; e < 8; ++e) acc[e] = fmaf(wgt, xv[e], acc[e]);
    }
#pragma unroll
    for (int e = 0; e < 8; ++e) {
        acc[e] += __shfl_xor(acc[e], 16);
        acc[e] += __shfl_xor(acc[e], 32);
    }
    __shared__ float sq[4][DD];
    if (l < 16) {
#pragma unroll
        for (int e = 0; e < 8; ++e) sq[w][qo + e] = acc[e];
    }
    __syncthreads();
    if (t < DD) {
        float v = sq[0][t] + sq[1][t] + sq[2][t] + sq[3][t];
        int rbq = row >> 7, rr = row & 127, rt2 = rr >> 5, lp = rr & 31;
        int k = t;
        qrh2[(((size_t)(rbq * 4 + rt2) * 8 + (k >> 4)) * 64
              + (lp + 32 * ((k >> 3) & 1))) * 8 + (k & 7)] = f2bf(v);
    }
}

// ---- K3: G-GEMM (32x32x16 MFMA), 4 waves x 64 rows x full-K, reg-resident --
// grid (rc=32, dq=16, js=4) = 2048 blocks, 256 thr (4 waves), 2 blocks/CU.
// Wave w owns rows [w*64, w*64+64) (2 rt), full K=128. Live set ~190 VGPR
// (Bf 64 + xv 32 + A 32 + acc 32 + sout 16 + addr) -> fits at 2 waves/SIMD
// WITHOUT SPILLS (the 50us plateau of r4/r5/r7 was scratch spill traffic).
// One 64 KB LDS buffer, phase-aliased: x-tile -> emb tile -> out staging.
__global__ __launch_bounds__(256, 2) void k3_gemm(
    const float* __restrict__ x, const short* __restrict__ embh3,
    const short* __restrict__ qrh2, float* __restrict__ part)
{
    __shared__ __align__(16) char ldsb[65536];
    short* xtwh = (short*)ldsb;          // phase 1: [256][36] bf16 (18 KB)
    short* elds = (short*)ldsb;          // phase 2: [8][4096] bf16 (64 KB)
    float* sof  = (float*)ldsb;          // phase 3: [256][8] f32 (8 KB)

    int t = threadIdx.x, w = t >> 6, l = t & 63;
    int l31 = l & 31, hi = l >> 5;
    int rc = blockIdx.x, dq = blockIdx.y, js = blockIdx.z;

    // phase 1: stage x tile (256 r x 32 j) as bf16
#pragma unroll
    for (int i = 0; i < 8; ++i) {
        int idx = i * 256 + t;
        int r = idx >> 3, j4 = (idx & 7) * 4;
        float4 v = *(const float4*)(x + (size_t)(rc * 256 + r) * 128 + js * 32 + j4);
        *(unsigned int*)(xtwh + r * 36 + j4)     = pack_bf16(v.x, v.y);
        *(unsigned int*)(xtwh + r * 36 + j4 + 2) = pack_bf16(v.z, v.w);
    }

    // B fragments: full K, 2 row-tiles (64 VGPR)
    bf16x8 Bf[2][8];
#pragma unroll
    for (int rt = 0; rt < 2; ++rt) {
        int R32 = rc * 8 + w * 2 + rt;
#pragma unroll
        for (int s = 0; s < 8; ++s)
            Bf[rt][s] = *(const bf16x8*)(qrh2
                + (((size_t)R32 * 8 + s) * 64 + l) * 8);
    }

    __syncthreads();

    // extract xv (f32, 32 VGPR)
    float xv[2][16];
#pragma unroll
    for (int rt = 0; rt < 2; ++rt) {
        int row_l = w * 64 + rt * 32 + l31;
#pragma unroll
        for (int p = 0; p < 8; ++p) {
            int jA = ((2 * p) & 3) + 8 * (p >> 1) + 4 * hi;
            unsigned int u = *(const unsigned int*)(xtwh + row_l * 36 + jA);
            xv[rt][2 * p]     = u2f(u << 16);
            xv[rt][2 * p + 1] = u2f(u & 0xFFFF0000u);
        }
    }

    __syncthreads();   // xtwh dead; overwrite with elds

    // phase 2: stage emb tile (8 d x 32 j x 128 k = 64 KB) via global_load_lds
#pragma unroll
    for (int i = 0; i < 16; ++i) {
        int c = i * 256 + t;
        int d = c >> 9, off = c & 511;
        gload_lds16(embh3 + (size_t)((dq * 8 + d) * 4 + js) * 4096 + (size_t)off * 8,
                    elds + (size_t)(i * 256 + w * 64) * 8);
    }
    __syncthreads();

    float sout[2][8];

#pragma unroll
    for (int d = 0; d < 8; ++d) {
        bf16x8 A[8];
#pragma unroll
        for (int s = 0; s < 8; ++s)
            A[s] = *(const bf16x8*)(elds + d * 4096 + (s * 64 + l) * 8);
#pragma unroll
        for (int rt = 0; rt < 2; ++rt) {
            f32x16 acc;
#pragma unroll
            for (int q = 0; q < 16; ++q) acc[q] = 0.f;
#pragma unroll
            for (int s = 0; s < 8; ++s)
                acc = __builtin_amdgcn_mfma_f32_32x32x16_bf16(A[s], Bf[rt][s],
                                                              acc, 0, 0, 0);
            float s0 = 0.f, s1 = 0.f, s2 = 0.f, s3 = 0.f;
#pragma unroll
            for (int q = 0; q < 4; ++q) {
                s0 = fmaf(xv[rt][q * 4 + 0], acc[q * 4 + 0], s0);
                s1 = fmaf(xv[rt][q * 4 + 1], acc[q * 4 + 1], s1);
                s2 = fmaf(xv[rt][q * 4 + 2], acc[q * 4 + 2], s2);
                s3 = fmaf(xv[rt][q * 4 + 3], acc[q * 4 + 3], s3);
            }
            float sm = (s0 + s1) + (s2 + s3);
            sm += __shfl_xor(sm, 32);
            sout[rt][d] = sm;
        }
    }

    __syncthreads();   // all waves done reading elds
    if (hi == 0) {
#pragma unroll
        for (int rt = 0; rt < 2; ++rt)
#pragma unroll
            for (int d = 0; d < 8; ++d)
                sof[(w * 64 + rt * 32 + l31) * 8 + d] = sout[rt][d];
    }
    __syncthreads();

    // coalesced writeout to f32 plane js
#pragma unroll
    for (int i = 0; i < 2; ++i) {
        int idx = i * 256 + t;
        int r = idx >> 1, q = (idx & 1) * 4;
        float4 v = *(const float4*)&sof[r * 8 + q];
        *(float4*)(part + (size_t)js * (NROWS * DD)
                   + (size_t)(rc * 256 + r) * 128 + dq * 8 + q) = v;
    }
}

// ---- K4: sum 4 f32 partials + x, LayerNorm ---------------------------------
__global__ __launch_bounds__(256) void k4_ln(
    const float* __restrict__ x, const float* __restrict__ part,
    const float* __restrict__ gamma, const float* __restrict__ beta,
    float* __restrict__ out)
{
    int wave = threadIdx.x >> 6, lane = threadIdx.x & 63;
    int row = blockIdx.x * 4 + wave;
    size_t base = (size_t)row * DD;
    float r0 = x[base + lane], r1 = x[base + lane + 64];
#pragma unroll
    for (int p = 0; p < 4; ++p) {
        r0 += part[(size_t)p * NROWS * DD + base + lane];
        r1 += part[(size_t)p * NROWS * DD + base + lane + 64];
    }
    float s = r0 + r1, s2 = r0 * r0 + r1 * r1;
#pragma unroll
    for (int off = 32; off > 0; off >>= 1) {
        s += __shfl_xor(s, off);
        s2 += __shfl_xor(s2, off);
    }
    float mu = s * (1.0f / DD);
    float var = s2 * (1.0f / DD) - mu * mu;
    var = fmaxf(var, 0.0f);
    float rs = rsqrtf(var + LN_EPSF);
    out[base + lane] = (r0 - mu) * rs * gamma[lane] + beta[lane];
    out[base + lane + 64] = (r1 - mu) * rs * gamma[lane + 64] + beta[lane + 64];
}

extern "C" void kernel_launch(void* const* d_in, const int* in_sizes, int n_in,
                              void* d_out, int out_size, void* d_ws, size_t ws_size,
                              hipStream_t stream) {
    const float* x     = (const float*)d_in[0];
    const float* Wq    = (const float*)d_in[1];
    const float* bq    = (const float*)d_in[2];
    const float* Wm    = (const float*)d_in[3];
    const float* bm    = (const float*)d_in[4];
    const float* Ww    = (const float*)d_in[5];
    const float* bw    = (const float*)d_in[6];
    const float* Wc    = (const float*)d_in[7];
    const float* bc    = (const float*)d_in[8];
    const float* emb   = (const float*)d_in[9];
    const float* gamma = (const float*)d_in[10];
    const float* beta  = (const float*)d_in[11];
    float* out = (float*)d_out;
    float* ws  = (float*)d_ws;

    short* embh3 = (short*)ws;                  // 4 MB
    short* qrh2  = (short*)(ws + 1048576);      // 2 MB
    float* scal  = ws + 1572864;
    float* part  = ws + 1605632;                // 16 MB (4 f32 planes)
    float* tr    = ws + 1605632;                // transients alias part
    short* xh2   = (short*)tr;
    short* xl2   = (short*)(tr + 524288);
    float* mq    = tr + 1048576;
    float* mo    = tr + 2097152;
    short* Wfrag = (short*)(tr + 3145728);

    hipLaunchKernelGGL(k0a_emb,   dim3(128, 4), dim3(256), 0, stream, emb, embh3);
    hipLaunchKernelGGL(k0w_split, dim3(256),    dim3(256), 0, stream, Wq, Wm, Wfrag);
    hipLaunchKernelGGL(k0c_xsplit,dim3(256),    dim3(256), 0, stream,
                       x, Ww, bw, Wc, bc, xh2, xl2, scal);
    hipLaunchKernelGGL(k1_mfma,   dim3(256),    dim3(256), 0, stream,
                       xh2, xl2, Wfrag, bq, bm, mq, mo, scal);
    hipLaunchKernelGGL(k2_qr,     dim3(8192),   dim3(256), 0, stream,
                       x, mq, mo, scal, qrh2);
    hipLaunchKernelGGL(k3_gemm,   dim3(32, 16, 4), dim3(256), 0, stream,
                       x, embh3, qrh2, part);
    hipLaunchKernelGGL(k4_ln,     dim3(2048),   dim3(256), 0, stream,
                       x, part, gamma, beta, out);
}